// Round 8
// baseline (1465.308 us; speedup 1.0000x reference)
//
#include <hip/hip_runtime.h>
#include <hip/hip_bf16.h>

#define T_STEPS 20
#define NSTEP   19
#define NN      192
#define DH      64
#define DE      32
#define NB      192      // grid blocks == rows; <= 256 CUs so all co-resident
#define NTH     256
#define CHUNK   56       // prefetched j-rows per LDS chunk

typedef unsigned long long ull;

// ---------------- workspace float offsets ----------------
enum : int {
  O_H     = 0,                 // committed h   [N][64]           (row-local)
  O_C     = O_H   + NN*DH,
  O_HW0   = O_C   + NN*DH,     // h entering gcn0 (LSTM out)      (CROSS-BLOCK)
  O_HW1   = O_HW0 + NN*DH,     // h entering gcn1 (gcn0 out)      (CROSS-BLOCK)
  O_CW    = O_HW1 + NN*DH,     // working c                       (row-local)
  O_OG    = O_CW  + NN*DH,     // LSTM o-gate                     (row-local)
  O_U1    = O_OG  + NN*DH,     // h_i-part of gate preact         (row-local)
  O_U20   = O_U1  + NN*DH,     // h_j-part, gcn0                  (CROSS-BLOCK)
  O_U21   = O_U20 + NN*DH,     // h_j-part, gcn1                  (CROSS-BLOCK)
  O_S1    = O_U21 + NN*DH,     // h_i-part of score               (row-local)
  O_S20   = O_S1  + NN,        //                                  (CROSS-BLOCK)
  O_S21   = O_S20 + NN,
  O_ACC   = O_S21 + NN,        // [19][4] stats (device atomics)
  O_WIHT  = O_ACC + NSTEP*4 + 4,   // [e][G]  8192  (read-only after init)
  O_WHHT  = O_WIHT + 8192,
  O_BIH   = O_WHHT + 16384,
  O_WIN   = O_BIH  + 256,
  O_BIN   = O_WIN  + 64,
  O_WRELF = O_BIN  + 32,
  O_BRELF = O_WRELF+ 128,
  O_WGR   = O_BRELF+ 64,
  O_WGH1T = O_WGR  + 4096,
  O_WGH2T = O_WGH1T+ 8192,
  O_BGATE = O_WGH2T+ 8192,
  O_WARR  = O_BGATE+ 128,
  O_WARH1 = O_WARR + 64,
  O_WARH2 = O_WARH1+ 128,
  O_BAR   = O_WARH2+ 128,
  O_WNEIT = O_BAR  + 4,
  O_WOUT  = O_WNEIT+ 8192,
  O_BOUT  = O_WOUT + 128,
  O_END   = O_BOUT + 2,
  O_GBAR  = (O_END + 63) & ~63     // barrier words (zeroed via hipMemsetAsync)
};

__device__ __forceinline__ float bf2f(__hip_bfloat16 v) { return __bfloat162float(v); }
__device__ __forceinline__ float sigm(float x) { return 1.0f / (1.0f + expf(-x)); }

// ---- point-coherent access (bypasses per-XCD L2; no cache-maintenance) ----
__device__ __forceinline__ float cld(float* p) {
  return __hip_atomic_load(p, __ATOMIC_RELAXED, __HIP_MEMORY_SCOPE_AGENT);
}
__device__ __forceinline__ void cst(float* p, float v) {
  __hip_atomic_store(p, v, __ATOMIC_RELAXED, __HIP_MEMORY_SCOPE_AGENT);
}
__device__ __forceinline__ ull cld64(const ull* p) {
  return __hip_atomic_load(p, __ATOMIC_RELAXED, __HIP_MEMORY_SCOPE_AGENT);
}

// dtype-flex input load / output store
__device__ __forceinline__ float ldf(const void* p, int idx, int isf32) {
  if (isf32) return ((const float*)p)[idx];
  return bf2f(((const __hip_bfloat16*)p)[idx]);
}
__device__ __forceinline__ void stf(void* p, int idx, float v, int isf32) {
  if (isf32) ((float*)p)[idx] = v;
  else       ((__hip_bfloat16*)p)[idx] = __float2bfloat16(v);
}

// ---- fence-free grid barrier, BUSY-SPIN variant (round-8 A/B change).
// Theory: r5/r6's s_sleep spin let DVFS drop core clocks (~5x latency bloat,
// VALUBusy 2.8%). Keep one wave per CU issuing dependent FMAs between polls
// to hold clocks up. Dummy chain pinned with empty inline asm.
__device__ __forceinline__ void gbar(unsigned* bar, unsigned gen, int grp) {
  __syncthreads();
  if (threadIdx.x == 0) {
    __builtin_amdgcn_s_waitcnt(0);
    unsigned a = __hip_atomic_fetch_add(&bar[grp*64], 1u, __ATOMIC_RELAXED, __HIP_MEMORY_SCOPE_AGENT);
    if (a == gen*24u - 1u) {
      unsigned m = __hip_atomic_fetch_add(&bar[512], 1u, __ATOMIC_RELAXED, __HIP_MEMORY_SCOPE_AGENT);
      if (m == gen*8u - 1u)
        __hip_atomic_store(&bar[576], gen, __ATOMIC_RELAXED, __HIP_MEMORY_SCOPE_AGENT);
    }
    float d0 = (float)(threadIdx.x + 1), d1 = 1.0000001f, d2 = 1e-30f;
    while (__hip_atomic_load(&bar[576], __ATOMIC_RELAXED, __HIP_MEMORY_SCOPE_AGENT) < gen) {
#pragma unroll
      for (int z = 0; z < 256; z++) {
        d0 = __builtin_fmaf(d0, d1, d2);
        __asm__ volatile("" : "+v"(d0));   // pin: forces real v_fma issue
      }
    }
    __asm__ volatile("" : "+v"(d0));       // keep chain observable
  }
  __syncthreads();
}

__global__ __launch_bounds__(NTH, 1) void k_all(
    float* __restrict__ F, unsigned* __restrict__ bar,
    const void* __restrict__ nabs, const void* __restrict__ nnorm,
    const int* __restrict__ seq,  const int* __restrict__ nei,
    void* __restrict__ out,
    const void* w_in,  const void* b_in,  const void* w_ih, const void* w_hh,
    const void* b_ih,  const void* b_hh,  const void* w_rel,const void* b_rel,
    const void* w_gate,const void* b_gate,const void* w_ar, const void* b_ar,
    const void* w_nei, const void* w_out, const void* b_out)
{
  __shared__ __attribute__((aligned(16))) float s_r[32*NN];       // [d][j] 24 KB
  __shared__ __attribute__((aligned(16))) float s_u2[CHUNK*DH];   // 14 KB
  __shared__ __attribute__((aligned(16))) float s_hw[CHUNK*DH];   // 14 KB
  __shared__ __attribute__((aligned(16))) float s_s2[NN];
  __shared__ float s_score[NN], s_pos[NN], s_neif[NN];
  __shared__ int   s_jlist[NN];
  __shared__ float s_red[4*DH], s_v1[4], s_msg[DH], s_hprep[DH], s_keep[DH];
  __shared__ float s_x[DE], s_hc[DH], s_cc[DH], s_gates[4*DH], s_h1[DH];
  __shared__ int   s_isf, s_nv;

  const int tid = threadIdx.x, wave = tid >> 6, lane = tid & 63;
  const int i = blockIdx.x;
  const int grp = i / 24;
  unsigned gen = 0;

  // ---- dtype detect (per block): fp32 reinterpreted as bf16 is wild-valued
  if (wave == 0) {
    const unsigned short* u = (const unsigned short*)w_gate;
    int bad = 0;
    for (int x = lane; x < 1024; x += 64) {
      float v = __uint_as_float(((unsigned)u[x]) << 16);
      if (!(fabsf(v) <= 4.0f)) bad++;
    }
    for (int o = 32; o >= 1; o >>= 1) bad += __shfl_xor(bad, o, 64);
    if (lane == 0) s_isf = (bad > 64);
  }
  __syncthreads();
  const int isf32 = s_isf;

  // ---- init: zero state, convert/transpose weights (coherent stores)
  {
    const int gid = i*NTH + tid, gs = NB*NTH;
    for (int x = gid; x < O_WIHT; x += gs) cst(&F[x], 0.f);
    for (int x = gid; x < NN*2;  x += gs) stf(out, (T_STEPS-1)*NN*2 + x, 0.f, isf32);
    for (int x = gid; x < 8192;  x += gs) { int e = x >> 8, G = x & 255; cst(&F[O_WIHT + x], ldf(w_ih, G*32 + e, isf32)); }
    for (int x = gid; x < 16384; x += gs) { int k = x >> 8, G = x & 255; cst(&F[O_WHHT + x], ldf(w_hh, G*64 + k, isf32)); }
    for (int x = gid; x < 256;   x += gs) cst(&F[O_BIH + x], ldf(b_ih, x, isf32) + ldf(b_hh, x, isf32));
    for (int x = gid; x < 64;    x += gs) cst(&F[O_WIN + x], ldf(w_in, x, isf32));
    for (int x = gid; x < 32;    x += gs) cst(&F[O_BIN + x], ldf(b_in, x, isf32));
    for (int x = gid; x < 128;   x += gs) cst(&F[O_WRELF + x], ldf(w_rel, x, isf32));
    for (int x = gid; x < 64;    x += gs) cst(&F[O_BRELF + x], ldf(b_rel, x, isf32));
    for (int x = gid; x < 4096;  x += gs) { int p = x >> 11, h = (x >> 5) & 63, d = x & 31;
      cst(&F[O_WGR + x], ldf(w_gate, p*10240 + h*160 + d, isf32)); }
    for (int x = gid; x < 8192;  x += gs) { int p = x >> 12, k = (x >> 6) & 63, h = x & 63;
      cst(&F[O_WGH1T + x], ldf(w_gate, p*10240 + h*160 + 32 + k, isf32)); }
    for (int x = gid; x < 8192;  x += gs) { int p = x >> 12, k = (x >> 6) & 63, h = x & 63;
      cst(&F[O_WGH2T + x], ldf(w_gate, p*10240 + h*160 + 96 + k, isf32)); }
    for (int x = gid; x < 128;   x += gs) cst(&F[O_BGATE + x], ldf(b_gate, x, isf32));
    for (int x = gid; x < 64;    x += gs) { int p = x >> 5, d = x & 31; cst(&F[O_WARR + x], ldf(w_ar, p*160 + d, isf32)); }
    for (int x = gid; x < 128;   x += gs) { int p = x >> 6, k = x & 63; cst(&F[O_WARH1 + x], ldf(w_ar, p*160 + 32 + k, isf32)); }
    for (int x = gid; x < 128;   x += gs) { int p = x >> 6, k = x & 63; cst(&F[O_WARH2 + x], ldf(w_ar, p*160 + 96 + k, isf32)); }
    for (int x = gid; x < 2;     x += gs) cst(&F[O_BAR + x], ldf(b_ar, x, isf32));
    for (int x = gid; x < 8192;  x += gs) { int p = x >> 12, k = (x >> 6) & 63, h = x & 63;
      cst(&F[O_WNEIT + x], ldf(w_nei, p*4096 + h*64 + k, isf32)); }
    for (int x = gid; x < 128;   x += gs) cst(&F[O_WOUT + x], ldf(w_out, x, isf32));
    for (int x = gid; x < 2;     x += gs) cst(&F[O_BOUT + x], ldf(b_out, x, isf32));
  }
  gbar(bar, ++gen, grp);

  // ---- LSTM for step t + prep for gcn0 (row-local)
  auto lstm_prep = [&](int t) {
    if (wave == 0) { s_hc[lane] = F[O_H + i*DH + lane]; s_cc[lane] = F[O_C + i*DH + lane]; }
    if (wave == 1 && lane < DE) {
      float nx = ldf(nnorm, (t*NN + i)*2 + 0, isf32);
      float ny = ldf(nnorm, (t*NN + i)*2 + 1, isf32);
      s_x[lane] = fmaxf(nx*F[O_WIN + lane*2] + ny*F[O_WIN + lane*2 + 1] + F[O_BIN + lane], 0.f);
    }
    __syncthreads();
    {
      int G = tid;
      float acc = F[O_BIH + G];
      for (int e = 0; e < DE; e++) acc += F[O_WIHT + e*256 + G] * s_x[e];
      for (int k = 0; k < DH; k++) acc += F[O_WHHT + k*256 + G] * s_hc[k];
      s_gates[G] = acc;
    }
    __syncthreads();
    if (wave == 0) {
      float ig = sigm(s_gates[lane]);
      float fg = sigm(s_gates[64 + lane]);
      float gg = tanhf(s_gates[128 + lane]);
      float og = sigm(s_gates[192 + lane]);
      float c1 = fg * s_cc[lane] + ig * gg;
      float h1 = og * tanhf(c1);
      int idx = i*DH + lane;
      F[O_CW  + idx] = c1;
      cst(&F[O_HW0 + idx], h1);
      F[O_OG  + idx] = og;
      s_h1[lane] = h1;
    }
    __syncthreads();
    {
      int idx = i*DH + lane;
      if (wave == 0) {
        float a = 0.f;
        const float* w = F + O_WGH1T + lane;
        for (int k = 0; k < DH; k++) a += w[k*DH] * s_h1[k];
        F[O_U1 + idx] = a;
      } else if (wave == 1) {
        float a = 0.f;
        const float* w = F + O_WGH2T + lane;
        for (int k = 0; k < DH; k++) a += w[k*DH] * s_h1[k];
        cst(&F[O_U20 + idx], a);
      } else if (wave == 2) {
        float hp = s_h1[lane];
        float a1 = hp * F[O_WARH1 + lane];
        float a2 = hp * F[O_WARH2 + lane];
        for (int o = 32; o >= 1; o >>= 1) { a1 += __shfl_xor(a1, o, 64); a2 += __shfl_xor(a2, o, 64); }
        if (lane == 0) { F[O_S1 + i] = a1; cst(&F[O_S20 + i], a2); }
      }
    }
  };

  lstm_prep(0);
  gbar(bar, ++gen, grp);

  // ================= main scan =================
  for (int ph = 0; ph < 2*NSTEP; ph++) {
    const int t = ph >> 1, p = ph & 1;
    const int m_i = seq[t*NN + i] > 0;
    const int HWr = p ? O_HW1 : O_HW0;
    const int U2r = p ? O_U21 : O_U20;
    const int S2r = p ? O_S21 : O_S20;

    // ---- S2 row prefetch (one batched coherent load round)
    if (tid < NN/2) {
      ull v = cld64((const ull*)(F + S2r) + tid);
      ((ull*)s_s2)[tid] = v;
    }
    __syncthreads();

    // ---- P1: mask, r values, raw scores
    if (wave < 3) {
      int j  = wave*64 + lane;
      int nf = m_i && (seq[t*NN + j] > 0) && (nei[(t*NN + i)*NN + j] > 0);
      s_neif[j] = nf ? 1.f : 0.f;
      float sc = 0.f;
      if (nf) {
        float cx = ldf(nabs, (t*NN + i)*2 + 0, isf32) - ldf(nabs, (t*NN + j)*2 + 0, isf32);
        float cy = ldf(nabs, (t*NN + i)*2 + 1, isf32) - ldf(nabs, (t*NN + j)*2 + 1, isf32);
        const float* wr = F + O_WRELF + p*64;
        const float* br = F + O_BRELF + p*32;
        const float* wa = F + O_WARR  + p*32;
        float dot = 0.f;
        for (int d = 0; d < 32; d++) {
          float rv = fmaxf(cx*wr[2*d] + cy*wr[2*d+1] + br[d], 0.f);
          s_r[d*NN + j] = rv;
          dot += rv * wa[d];
        }
        sc = dot + F[O_S1 + i] + s_s2[j] + F[O_BAR + p];
      }
      s_score[j] = sc;
    }
    __syncthreads();

    // ---- P2: masked softmax + j-list compaction + (p==0) row stats (wave 0)
    if (wave == 0) {
      float n0 = s_neif[lane], n1 = s_neif[64+lane], n2 = s_neif[128+lane];
      float sc0 = s_score[lane], sc1 = s_score[64+lane], sc2 = s_score[128+lane];
      const float NEG = -3.0e38f;
      float mx = fmaxf(fmaxf(n0 > 0.f ? sc0 : NEG, n1 > 0.f ? sc1 : NEG),
                       n2 > 0.f ? sc2 : NEG);
      for (int o = 32; o >= 1; o >>= 1) mx = fmaxf(mx, __shfl_xor(mx, o, 64));
      float e0 = (n0 > 0.f) ? expf(sc0 - mx) : 0.f;
      float e1 = (n1 > 0.f) ? expf(sc1 - mx) : 0.f;
      float e2 = (n2 > 0.f) ? expf(sc2 - mx) : 0.f;
      float s = e0 + e1 + e2;
      for (int o = 32; o >= 1; o >>= 1) s += __shfl_xor(s, o, 64);
      float inv = (s > 0.f) ? 1.0f / s : 0.f;
      float p0 = e0*inv, p1 = e1*inv, p2 = e2*inv;
      s_pos[lane] = p0; s_pos[64+lane] = p1; s_pos[128+lane] = p2;
      ull m0 = __ballot(n0 > 0.f), m1 = __ballot(n1 > 0.f), m2 = __ballot(n2 > 0.f);
      ull lt = (1ull << lane) - 1ull;
      int c0 = __popcll(m0), c1 = __popcll(m1);
      if (n0 > 0.f) s_jlist[__popcll(m0 & lt)] = lane;
      if (n1 > 0.f) s_jlist[c0 + __popcll(m1 & lt)] = 64 + lane;
      if (n2 > 0.f) s_jlist[c0 + c1 + __popcll(m2 & lt)] = 128 + lane;
      if (lane == 0) s_nv = c0 + c1 + __popcll(m2);
      if (p == 0 && m_i) {
        float cnt = n0 + n1 + n2;
        float pm  = fmaxf(fmaxf(p0, p1), p2);
        for (int o = 32; o >= 1; o >>= 1) {
          cnt += __shfl_xor(cnt, o, 64);
          pm   = fmaxf(pm, __shfl_xor(pm, o, 64));
        }
        if (lane == 0 && cnt > 0.f) {
          atomicAdd(&F[O_ACC + t*4 + 1], cnt);
          atomicAdd(&F[O_ACC + t*4 + 2], pm);
          atomicAdd(&F[O_ACC + t*4 + 3], 1.f);
        }
      }
    }
    __syncthreads();

    // ---- P3: chunked LDS gather of U2/HW rows, then pure-LDS gate+msg
    {
      float msg = 0.f, v1 = 0.f;
      const int nv = s_nv;
      float wreg[32];
      float basev = 0.f;
      if (nv > 0) {
#pragma unroll
        for (int d = 0; d < 32; d++) wreg[d] = F[O_WGR + p*2048 + lane*32 + d];
        basev = F[O_U1 + i*DH + lane] + F[O_BGATE + p*DH + lane];
      }
      const ull* U64 = (const ull*)(F + U2r);
      const ull* H64 = (const ull*)(F + HWr);
      ull* su = (ull*)s_u2;
      ull* sh = (ull*)s_hw;
      for (int b = 0; b < nv; b += CHUNK) {
        if (b > 0) __syncthreads();
        const int cn = (nv - b < CHUNK) ? (nv - b) : CHUNK;
        const int total = cn * 32;                  // 32 u64 per 64-float row
        for (int id = tid; id < total; id += 2*NTH) {
          int kk1 = id >> 5, q1 = id & 31;
          int j1 = s_jlist[b + kk1];
          ull a1 = cld64(U64 + j1*32 + q1);
          ull h1v = cld64(H64 + j1*32 + q1);
          int id2 = id + NTH;
          if (id2 < total) {
            int kk2 = id2 >> 5, q2 = id2 & 31;
            int j2 = s_jlist[b + kk2];
            ull a2 = cld64(U64 + j2*32 + q2);
            ull h2v = cld64(H64 + j2*32 + q2);
            su[kk1*32 + q1] = a1; sh[kk1*32 + q1] = h1v;
            su[kk2*32 + q2] = a2; sh[kk2*32 + q2] = h2v;
          } else {
            su[kk1*32 + q1] = a1; sh[kk1*32 + q1] = h1v;
          }
        }
        __syncthreads();
        if (m_i) {
          for (int kk = wave; kk < cn; kk += 4) {
            int j = s_jlist[b + kk];
            float acc = basev + s_u2[kk*DH + lane];
#pragma unroll
            for (int d = 0; d < 32; d++) acc += s_r[d*NN + j] * wreg[d];
            float g = 1.0f / (1.0f + expf(-acc));
            v1 += g;
            msg += s_pos[j] * g * s_hw[kk*DH + lane];
          }
        }
      }
      s_red[wave*DH + lane] = msg;
      for (int o = 32; o >= 1; o >>= 1) v1 += __shfl_xor(v1, o, 64);
      if (lane == 0) s_v1[wave] = v1;
    }
    __syncthreads();

    // ---- T1: combine partials + v1 atomic (wave 0)
    if (wave == 0) {
      s_msg[lane] = s_red[lane] + s_red[64+lane] + s_red[128+lane] + s_red[192+lane];
      if (p == 0 && m_i && lane == 0) {
        float v1t = s_v1[0] + s_v1[1] + s_v1[2] + s_v1[3];
        atomicAdd(&F[O_ACC + t*4 + 0], v1t);
      }
    }
    __syncthreads();

    // ---- T2: c/h update; publish (p=0) or commit (p=1). No coherent reads:
    // own-row h carried in LDS (s_h1 = LSTM out; s_keep = post-gcn0 h).
    if (wave == 0) {
      int idx = i*DH + lane;
      float hcom;
      if (m_i) {
        float cn = F[O_CW + idx];
        const float* wn = F + O_WNEIT + p*4096 + lane;
        for (int k = 0; k < DH; k++) cn += s_msg[k] * wn[k*DH];
        hcom = F[O_OG + idx] * tanhf(cn);
        F[O_CW + idx] = cn;
        if (p == 1) { F[O_H + idx] = hcom; F[O_C + idx] = cn; }
      } else {
        hcom = (p == 0) ? s_h1[lane] : s_keep[lane];  // gcn identity for masked
      }
      if (p == 0) { cst(&F[O_HW1 + idx], hcom); s_keep[lane] = hcom; }
      s_hprep[lane] = hcom;
    }
    __syncthreads();

    if (p == 0) {
      // ---- PREP for p=1 from post-gcn0 h
      int idx = i*DH + lane;
      if (wave == 0) {
        float a = 0.f;
        const float* w = F + O_WGH1T + 4096 + lane;
        for (int k = 0; k < DH; k++) a += w[k*DH] * s_hprep[k];
        F[O_U1 + idx] = a;
      } else if (wave == 1) {
        float a = 0.f;
        const float* w = F + O_WGH2T + 4096 + lane;
        for (int k = 0; k < DH; k++) a += w[k*DH] * s_hprep[k];
        cst(&F[O_U21 + idx], a);
      } else if (wave == 2) {
        float hp = s_hprep[lane];
        float a1 = hp * F[O_WARH1 + DH + lane];
        float a2 = hp * F[O_WARH2 + DH + lane];
        for (int o = 32; o >= 1; o >>= 1) { a1 += __shfl_xor(a1, o, 64); a2 += __shfl_xor(a2, o, 64); }
        if (lane == 0) { F[O_S1 + i] = a1; cst(&F[O_S21 + i], a2); }
      }
    } else {
      // ---- OUT for step t
      if (wave == 0 && lane < 2) {
        float a = 0.f;
        if (m_i) {
          a = F[O_BOUT + lane];
          const float* wo = F + O_WOUT + lane*DH;
          for (int h = 0; h < DH; h++) a += s_hprep[h] * wo[h];
        }
        stf(out, (t*NN + i)*2 + lane, a, isf32);
      }
      // ---- fused LSTM(t+1) + prep p=0 (row-local)
      if (t < NSTEP - 1) { __syncthreads(); lstm_prep(t + 1); }
    }
    if (ph != 2*NSTEP - 1) gbar(bar, ++gen, grp);  // last phase: no barrier needed
  }

  // ---- finalize: own h/c rows + (block 0) scalars
  if (wave == 0) {
    stf(out, T_STEPS*NN*2 + i*DH + lane,          F[O_H + i*DH + lane], isf32);
    stf(out, T_STEPS*NN*2 + NN*DH + i*DH + lane,  F[O_C + i*DH + lane], isf32);
  }
  if (i == 0 && tid == 0) {
    float v1 = 0.f, v2 = 0.f, v3 = 0.f;
    for (int t = 0; t < NSTEP; t++) {
      float sg = cld(&F[O_ACC + t*4 + 0]), sn = cld(&F[O_ACC + t*4 + 1]);
      float sp = cld(&F[O_ACC + t*4 + 2]), sm = cld(&F[O_ACC + t*4 + 3]);
      v1 += sg / (sn * 64.f + 1e-6f);
      v2 += sp / (sm + 1e-6f);
      v3 += sn / 192.f;
    }
    int base = T_STEPS*NN*2 + 2*NN*DH;
    stf(out, base + 0, v1 / 20.f, isf32);
    stf(out, base + 1, v2 / 20.f, isf32);
    stf(out, base + 2, v3 / 20.f, isf32);
  }
}

extern "C" void kernel_launch(void* const* d_in, const int* in_sizes, int n_in,
                              void* d_out, int out_size, void* d_ws, size_t ws_size,
                              hipStream_t stream) {
  float* F = (float*)d_ws;
  unsigned* bar = (unsigned*)(F + O_GBAR);
  hipMemsetAsync((void*)bar, 0, 4096, stream);
  k_all<<<NB, NTH, 0, stream>>>(
      F, bar,
      d_in[0], d_in[1], (const int*)d_in[18], (const int*)d_in[19], d_out,
      d_in[3], d_in[4], d_in[5], d_in[6], d_in[7], d_in[8], d_in[9], d_in[10],
      d_in[11], d_in[12], d_in[13], d_in[14], d_in[15], d_in[16], d_in[17]);
}

// Round 9
// 1452.377 us; speedup vs baseline: 1.0089x; 1.0089x over previous
//
#include <hip/hip_runtime.h>
#include <hip/hip_bf16.h>

#define T_STEPS 20
#define NSTEP   19
#define NN      192
#define DH      64
#define DE      32
#define NB      192      // grid blocks == rows; <= 256 CUs so all co-resident
#define NTH     256
#define CHUNK   56       // prefetched j-rows per LDS chunk

typedef unsigned long long ull;

// ---------------- workspace float offsets ----------------
enum : int {
  O_H     = 0,                 // committed h   [N][64]           (row-local)
  O_C     = O_H   + NN*DH,
  O_HW0   = O_C   + NN*DH,     // h entering gcn0 (LSTM out)      (CROSS-BLOCK)
  O_HW1   = O_HW0 + NN*DH,     // h entering gcn1 (gcn0 out)      (CROSS-BLOCK)
  O_CW    = O_HW1 + NN*DH,     // working c                       (row-local)
  O_OG    = O_CW  + NN*DH,     // LSTM o-gate                     (row-local)
  O_U1    = O_OG  + NN*DH,     // h_i-part of gate preact         (row-local)
  O_U20   = O_U1  + NN*DH,     // h_j-part, gcn0                  (CROSS-BLOCK)
  O_U21   = O_U20 + NN*DH,     // h_j-part, gcn1                  (CROSS-BLOCK)
  O_S1    = O_U21 + NN*DH,     // h_i-part of score               (row-local)
  O_S20   = O_S1  + NN,        //                                  (CROSS-BLOCK)
  O_S21   = O_S20 + NN,
  O_ACC   = O_S21 + NN,        // [19][4] stats (device atomics)
  O_WIHT  = O_ACC + NSTEP*4 + 4,   // [e][G]  8192  (read-only after init)
  O_WHHT  = O_WIHT + 8192,
  O_BIH   = O_WHHT + 16384,
  O_WIN   = O_BIH  + 256,
  O_BIN   = O_WIN  + 64,
  O_WRELF = O_BIN  + 32,
  O_BRELF = O_WRELF+ 128,
  O_WGR   = O_BRELF+ 64,
  O_WGH1T = O_WGR  + 4096,
  O_WGH2T = O_WGH1T+ 8192,
  O_BGATE = O_WGH2T+ 8192,
  O_WARR  = O_BGATE+ 128,
  O_WARH1 = O_WARR + 64,
  O_WARH2 = O_WARH1+ 128,
  O_BAR   = O_WARH2+ 128,
  O_WNEIT = O_BAR  + 4,
  O_WOUT  = O_WNEIT+ 8192,
  O_BOUT  = O_WOUT + 128,
  O_END   = O_BOUT + 2,
  O_GBAR  = (O_END + 63) & ~63     // barrier words (zeroed via hipMemsetAsync)
};

__device__ __forceinline__ float bf2f(__hip_bfloat16 v) { return __bfloat162float(v); }
__device__ __forceinline__ float sigm(float x) { return 1.0f / (1.0f + __expf(-x)); }
__device__ __forceinline__ float tanh_fast(float x) {
  float e = __expf(-2.0f * fabsf(x));
  float r = (1.0f - e) / (1.0f + e);
  return copysignf(r, x);
}

// ---- point-coherent data access (agent relaxed; proven correct r5-r8) ----
__device__ __forceinline__ float cld(float* p) {
  return __hip_atomic_load(p, __ATOMIC_RELAXED, __HIP_MEMORY_SCOPE_AGENT);
}
__device__ __forceinline__ void cst(float* p, float v) {
  __hip_atomic_store(p, v, __ATOMIC_RELAXED, __HIP_MEMORY_SCOPE_AGENT);
}
__device__ __forceinline__ ull cld64(const ull* p) {
  return __hip_atomic_load(p, __ATOMIC_RELAXED, __HIP_MEMORY_SCOPE_AGENT);
}

// dtype-flex input load / output store
__device__ __forceinline__ float ldf(const void* p, int idx, int isf32) {
  if (isf32) return ((const float*)p)[idx];
  return bf2f(((const __hip_bfloat16*)p)[idx]);
}
__device__ __forceinline__ void stf(void* p, int idx, float v, int isf32) {
  if (isf32) ((float*)p)[idx] = v;
  else       ((__hip_bfloat16*)p)[idx] = __float2bfloat16(v);
}

// ---- r9 barrier: two-hop hierarchical broadcast, system-scope, RMW flags ----
// Layout (word idx, separate 128B lines): arr[g]=g*32 (g<8) · master=256 ·
// mflag=288 · gflag[g]=320+g*32. Flags advance by fetch_add(1) per generation
// (RMW confirms LLC visibility — plain stores could linger in the CU write
// path while the producer sleeps). Same-line pollers: 8 on mflag, <=23 on
// gflag[g] (was 192 on one flag — suspected LLC slice serialization).
__device__ __forceinline__ unsigned bfa(unsigned* p) {
  return __hip_atomic_fetch_add(p, 1u, __ATOMIC_RELAXED, __HIP_MEMORY_SCOPE_SYSTEM);
}
__device__ __forceinline__ unsigned bld(unsigned* p) {
  return __hip_atomic_load(p, __ATOMIC_RELAXED, __HIP_MEMORY_SCOPE_SYSTEM);
}
__device__ __forceinline__ void gbar(unsigned* bar, unsigned gen, int grp) {
  __syncthreads();
  if (threadIdx.x == 0) {
    __builtin_amdgcn_s_waitcnt(0);
    unsigned a = bfa(&bar[grp*32]);
    if (a == gen*24u - 1u) {                 // last arriver of this group
      unsigned m = bfa(&bar[256]);
      if (m == gen*8u - 1u) {
        bfa(&bar[288]);                      // mflag := gen (RMW; visible now)
      } else {
        while (bld(&bar[288]) < gen) __builtin_amdgcn_s_sleep(4);
      }
      bfa(&bar[320 + grp*32]);               // gflag[grp] := gen
    } else {
      while (bld(&bar[320 + grp*32]) < gen) __builtin_amdgcn_s_sleep(4);
    }
  }
  __syncthreads();
}

__global__ __launch_bounds__(NTH, 1) void k_all(
    float* __restrict__ F, unsigned* __restrict__ bar,
    const void* __restrict__ nabs, const void* __restrict__ nnorm,
    const int* __restrict__ seq,  const int* __restrict__ nei,
    void* __restrict__ out,
    const void* w_in,  const void* b_in,  const void* w_ih, const void* w_hh,
    const void* b_ih,  const void* b_hh,  const void* w_rel,const void* b_rel,
    const void* w_gate,const void* b_gate,const void* w_ar, const void* b_ar,
    const void* w_nei, const void* w_out, const void* b_out)
{
  __shared__ __attribute__((aligned(16))) float s_r[32*NN];       // [d][j] 24 KB
  __shared__ __attribute__((aligned(16))) float s_u2[CHUNK*DH];   // 14 KB
  __shared__ __attribute__((aligned(16))) float s_hw[CHUNK*DH];   // 14 KB
  __shared__ __attribute__((aligned(16))) float s_s2[NN];
  __shared__ float s_score[NN], s_pos[NN], s_neif[NN];
  __shared__ int   s_jlist[NN];
  __shared__ float s_red[4*DH], s_v1[4], s_msg[DH], s_hprep[DH], s_keep[DH];
  __shared__ float s_x[DE], s_hc[DH], s_cc[DH], s_gates[4*DH], s_h1[DH];
  __shared__ int   s_isf, s_nv;

  const int tid = threadIdx.x, wave = tid >> 6, lane = tid & 63;
  const int i = blockIdx.x;
  const int grp = i / 24;
  unsigned gen = 0;

  // ---- dtype detect (per block): fp32 reinterpreted as bf16 is wild-valued
  if (wave == 0) {
    const unsigned short* u = (const unsigned short*)w_gate;
    int bad = 0;
    for (int x = lane; x < 1024; x += 64) {
      float v = __uint_as_float(((unsigned)u[x]) << 16);
      if (!(fabsf(v) <= 4.0f)) bad++;
    }
    for (int o = 32; o >= 1; o >>= 1) bad += __shfl_xor(bad, o, 64);
    if (lane == 0) s_isf = (bad > 64);
  }
  __syncthreads();
  const int isf32 = s_isf;

  // ---- init: zero state, convert/transpose weights (coherent stores)
  {
    const int gid = i*NTH + tid, gs = NB*NTH;
    for (int x = gid; x < O_WIHT; x += gs) cst(&F[x], 0.f);
    for (int x = gid; x < NN*2;  x += gs) stf(out, (T_STEPS-1)*NN*2 + x, 0.f, isf32);
    for (int x = gid; x < 8192;  x += gs) { int e = x >> 8, G = x & 255; cst(&F[O_WIHT + x], ldf(w_ih, G*32 + e, isf32)); }
    for (int x = gid; x < 16384; x += gs) { int k = x >> 8, G = x & 255; cst(&F[O_WHHT + x], ldf(w_hh, G*64 + k, isf32)); }
    for (int x = gid; x < 256;   x += gs) cst(&F[O_BIH + x], ldf(b_ih, x, isf32) + ldf(b_hh, x, isf32));
    for (int x = gid; x < 64;    x += gs) cst(&F[O_WIN + x], ldf(w_in, x, isf32));
    for (int x = gid; x < 32;    x += gs) cst(&F[O_BIN + x], ldf(b_in, x, isf32));
    for (int x = gid; x < 128;   x += gs) cst(&F[O_WRELF + x], ldf(w_rel, x, isf32));
    for (int x = gid; x < 64;    x += gs) cst(&F[O_BRELF + x], ldf(b_rel, x, isf32));
    for (int x = gid; x < 4096;  x += gs) { int p = x >> 11, h = (x >> 5) & 63, d = x & 31;
      cst(&F[O_WGR + x], ldf(w_gate, p*10240 + h*160 + d, isf32)); }
    for (int x = gid; x < 8192;  x += gs) { int p = x >> 12, k = (x >> 6) & 63, h = x & 63;
      cst(&F[O_WGH1T + x], ldf(w_gate, p*10240 + h*160 + 32 + k, isf32)); }
    for (int x = gid; x < 8192;  x += gs) { int p = x >> 12, k = (x >> 6) & 63, h = x & 63;
      cst(&F[O_WGH2T + x], ldf(w_gate, p*10240 + h*160 + 96 + k, isf32)); }
    for (int x = gid; x < 128;   x += gs) cst(&F[O_BGATE + x], ldf(b_gate, x, isf32));
    for (int x = gid; x < 64;    x += gs) { int p = x >> 5, d = x & 31; cst(&F[O_WARR + x], ldf(w_ar, p*160 + d, isf32)); }
    for (int x = gid; x < 128;   x += gs) { int p = x >> 6, k = x & 63; cst(&F[O_WARH1 + x], ldf(w_ar, p*160 + 32 + k, isf32)); }
    for (int x = gid; x < 128;   x += gs) { int p = x >> 6, k = x & 63; cst(&F[O_WARH2 + x], ldf(w_ar, p*160 + 96 + k, isf32)); }
    for (int x = gid; x < 2;     x += gs) cst(&F[O_BAR + x], ldf(b_ar, x, isf32));
    for (int x = gid; x < 8192;  x += gs) { int p = x >> 12, k = (x >> 6) & 63, h = x & 63;
      cst(&F[O_WNEIT + x], ldf(w_nei, p*4096 + h*64 + k, isf32)); }
    for (int x = gid; x < 128;   x += gs) cst(&F[O_WOUT + x], ldf(w_out, x, isf32));
    for (int x = gid; x < 2;     x += gs) cst(&F[O_BOUT + x], ldf(b_out, x, isf32));
  }
  gbar(bar, ++gen, grp);

  // ---- LSTM for step t + prep for gcn0 (row-local)
  auto lstm_prep = [&](int t) {
    if (wave == 0) { s_hc[lane] = F[O_H + i*DH + lane]; s_cc[lane] = F[O_C + i*DH + lane]; }
    if (wave == 1 && lane < DE) {
      float nx = ldf(nnorm, (t*NN + i)*2 + 0, isf32);
      float ny = ldf(nnorm, (t*NN + i)*2 + 1, isf32);
      s_x[lane] = fmaxf(nx*F[O_WIN + lane*2] + ny*F[O_WIN + lane*2 + 1] + F[O_BIN + lane], 0.f);
    }
    __syncthreads();
    {
      int G = tid;
      float acc = F[O_BIH + G];
      for (int e = 0; e < DE; e++) acc += F[O_WIHT + e*256 + G] * s_x[e];
      for (int k = 0; k < DH; k++) acc += F[O_WHHT + k*256 + G] * s_hc[k];
      s_gates[G] = acc;
    }
    __syncthreads();
    if (wave == 0) {
      float ig = sigm(s_gates[lane]);
      float fg = sigm(s_gates[64 + lane]);
      float gg = tanh_fast(s_gates[128 + lane]);
      float og = sigm(s_gates[192 + lane]);
      float c1 = fg * s_cc[lane] + ig * gg;
      float h1 = og * tanh_fast(c1);
      int idx = i*DH + lane;
      F[O_CW  + idx] = c1;
      cst(&F[O_HW0 + idx], h1);
      F[O_OG  + idx] = og;
      s_h1[lane] = h1;
    }
    __syncthreads();
    {
      int idx = i*DH + lane;
      if (wave == 0) {
        float a = 0.f;
        const float* w = F + O_WGH1T + lane;
        for (int k = 0; k < DH; k++) a += w[k*DH] * s_h1[k];
        F[O_U1 + idx] = a;
      } else if (wave == 1) {
        float a = 0.f;
        const float* w = F + O_WGH2T + lane;
        for (int k = 0; k < DH; k++) a += w[k*DH] * s_h1[k];
        cst(&F[O_U20 + idx], a);
      } else if (wave == 2) {
        float hp = s_h1[lane];
        float a1 = hp * F[O_WARH1 + lane];
        float a2 = hp * F[O_WARH2 + lane];
        for (int o = 32; o >= 1; o >>= 1) { a1 += __shfl_xor(a1, o, 64); a2 += __shfl_xor(a2, o, 64); }
        if (lane == 0) { F[O_S1 + i] = a1; cst(&F[O_S20 + i], a2); }
      }
    }
  };

  lstm_prep(0);
  gbar(bar, ++gen, grp);

  // ================= main scan =================
  for (int ph = 0; ph < 2*NSTEP; ph++) {
    const int t = ph >> 1, p = ph & 1;
    const int m_i = seq[t*NN + i] > 0;
    const int HWr = p ? O_HW1 : O_HW0;
    const int U2r = p ? O_U21 : O_U20;
    const int S2r = p ? O_S21 : O_S20;

    // ---- S2 row prefetch (one batched coherent load round)
    if (tid < NN/2) {
      ull v = cld64((const ull*)(F + S2r) + tid);
      ((ull*)s_s2)[tid] = v;
    }
    __syncthreads();

    // ---- P1: mask, r values, raw scores
    if (wave < 3) {
      int j  = wave*64 + lane;
      int nf = m_i && (seq[t*NN + j] > 0) && (nei[(t*NN + i)*NN + j] > 0);
      s_neif[j] = nf ? 1.f : 0.f;
      float sc = 0.f;
      if (nf) {
        float cx = ldf(nabs, (t*NN + i)*2 + 0, isf32) - ldf(nabs, (t*NN + j)*2 + 0, isf32);
        float cy = ldf(nabs, (t*NN + i)*2 + 1, isf32) - ldf(nabs, (t*NN + j)*2 + 1, isf32);
        const float* wr = F + O_WRELF + p*64;
        const float* br = F + O_BRELF + p*32;
        const float* wa = F + O_WARR  + p*32;
        float dot = 0.f;
        for (int d = 0; d < 32; d++) {
          float rv = fmaxf(cx*wr[2*d] + cy*wr[2*d+1] + br[d], 0.f);
          s_r[d*NN + j] = rv;
          dot += rv * wa[d];
        }
        sc = dot + F[O_S1 + i] + s_s2[j] + F[O_BAR + p];
      }
      s_score[j] = sc;
    }
    __syncthreads();

    // ---- P2: masked softmax + j-list compaction + (p==0) row stats (wave 0)
    if (wave == 0) {
      float n0 = s_neif[lane], n1 = s_neif[64+lane], n2 = s_neif[128+lane];
      float sc0 = s_score[lane], sc1 = s_score[64+lane], sc2 = s_score[128+lane];
      const float NEG = -3.0e38f;
      float mx = fmaxf(fmaxf(n0 > 0.f ? sc0 : NEG, n1 > 0.f ? sc1 : NEG),
                       n2 > 0.f ? sc2 : NEG);
      for (int o = 32; o >= 1; o >>= 1) mx = fmaxf(mx, __shfl_xor(mx, o, 64));
      float e0 = (n0 > 0.f) ? __expf(sc0 - mx) : 0.f;
      float e1 = (n1 > 0.f) ? __expf(sc1 - mx) : 0.f;
      float e2 = (n2 > 0.f) ? __expf(sc2 - mx) : 0.f;
      float s = e0 + e1 + e2;
      for (int o = 32; o >= 1; o >>= 1) s += __shfl_xor(s, o, 64);
      float inv = (s > 0.f) ? 1.0f / s : 0.f;
      float p0 = e0*inv, p1 = e1*inv, p2 = e2*inv;
      s_pos[lane] = p0; s_pos[64+lane] = p1; s_pos[128+lane] = p2;
      ull m0 = __ballot(n0 > 0.f), m1 = __ballot(n1 > 0.f), m2 = __ballot(n2 > 0.f);
      ull lt = (1ull << lane) - 1ull;
      int c0 = __popcll(m0), c1 = __popcll(m1);
      if (n0 > 0.f) s_jlist[__popcll(m0 & lt)] = lane;
      if (n1 > 0.f) s_jlist[c0 + __popcll(m1 & lt)] = 64 + lane;
      if (n2 > 0.f) s_jlist[c0 + c1 + __popcll(m2 & lt)] = 128 + lane;
      if (lane == 0) s_nv = c0 + c1 + __popcll(m2);
      if (p == 0 && m_i) {
        float cnt = n0 + n1 + n2;
        float pm  = fmaxf(fmaxf(p0, p1), p2);
        for (int o = 32; o >= 1; o >>= 1) {
          cnt += __shfl_xor(cnt, o, 64);
          pm   = fmaxf(pm, __shfl_xor(pm, o, 64));
        }
        if (lane == 0 && cnt > 0.f) {
          atomicAdd(&F[O_ACC + t*4 + 1], cnt);
          atomicAdd(&F[O_ACC + t*4 + 2], pm);
          atomicAdd(&F[O_ACC + t*4 + 3], 1.f);
        }
      }
    }
    __syncthreads();

    // ---- P3: chunked LDS gather of U2/HW rows, then pure-LDS gate+msg
    {
      float msg = 0.f, v1 = 0.f;
      const int nv = s_nv;
      float wreg[32];
      float basev = 0.f;
      if (nv > 0) {
#pragma unroll
        for (int d = 0; d < 32; d++) wreg[d] = F[O_WGR + p*2048 + lane*32 + d];
        basev = F[O_U1 + i*DH + lane] + F[O_BGATE + p*DH + lane];
      }
      const ull* U64 = (const ull*)(F + U2r);
      const ull* H64 = (const ull*)(F + HWr);
      ull* su = (ull*)s_u2;
      ull* sh = (ull*)s_hw;
      for (int b = 0; b < nv; b += CHUNK) {
        if (b > 0) __syncthreads();
        const int cn = (nv - b < CHUNK) ? (nv - b) : CHUNK;
        const int total = cn * 32;                  // 32 u64 per 64-float row
        for (int id = tid; id < total; id += 2*NTH) {
          int kk1 = id >> 5, q1 = id & 31;
          int j1 = s_jlist[b + kk1];
          ull a1 = cld64(U64 + j1*32 + q1);
          ull h1v = cld64(H64 + j1*32 + q1);
          int id2 = id + NTH;
          if (id2 < total) {
            int kk2 = id2 >> 5, q2 = id2 & 31;
            int j2 = s_jlist[b + kk2];
            ull a2 = cld64(U64 + j2*32 + q2);
            ull h2v = cld64(H64 + j2*32 + q2);
            su[kk1*32 + q1] = a1; sh[kk1*32 + q1] = h1v;
            su[kk2*32 + q2] = a2; sh[kk2*32 + q2] = h2v;
          } else {
            su[kk1*32 + q1] = a1; sh[kk1*32 + q1] = h1v;
          }
        }
        __syncthreads();
        if (m_i) {
          for (int kk = wave; kk < cn; kk += 4) {
            int j = s_jlist[b + kk];
            float acc = basev + s_u2[kk*DH + lane];
#pragma unroll
            for (int d = 0; d < 32; d++) acc += s_r[d*NN + j] * wreg[d];
            float g = sigm(acc);
            v1 += g;
            msg += s_pos[j] * g * s_hw[kk*DH + lane];
          }
        }
      }
      s_red[wave*DH + lane] = msg;
      for (int o = 32; o >= 1; o >>= 1) v1 += __shfl_xor(v1, o, 64);
      if (lane == 0) s_v1[wave] = v1;
    }
    __syncthreads();

    // ---- T1: combine partials + v1 atomic (wave 0)
    if (wave == 0) {
      s_msg[lane] = s_red[lane] + s_red[64+lane] + s_red[128+lane] + s_red[192+lane];
      if (p == 0 && m_i && lane == 0) {
        float v1t = s_v1[0] + s_v1[1] + s_v1[2] + s_v1[3];
        atomicAdd(&F[O_ACC + t*4 + 0], v1t);
      }
    }
    __syncthreads();

    // ---- T2: c/h update; publish (p=0) or commit (p=1). Own-row h in LDS.
    if (wave == 0) {
      int idx = i*DH + lane;
      float hcom;
      if (m_i) {
        float cn = F[O_CW + idx];
        const float* wn = F + O_WNEIT + p*4096 + lane;
        for (int k = 0; k < DH; k++) cn += s_msg[k] * wn[k*DH];
        hcom = F[O_OG + idx] * tanh_fast(cn);
        F[O_CW + idx] = cn;
        if (p == 1) { F[O_H + idx] = hcom; F[O_C + idx] = cn; }
      } else {
        hcom = (p == 0) ? s_h1[lane] : s_keep[lane];  // gcn identity for masked
      }
      if (p == 0) { cst(&F[O_HW1 + idx], hcom); s_keep[lane] = hcom; }
      s_hprep[lane] = hcom;
    }
    __syncthreads();

    if (p == 0) {
      // ---- PREP for p=1 from post-gcn0 h
      int idx = i*DH + lane;
      if (wave == 0) {
        float a = 0.f;
        const float* w = F + O_WGH1T + 4096 + lane;
        for (int k = 0; k < DH; k++) a += w[k*DH] * s_hprep[k];
        F[O_U1 + idx] = a;
      } else if (wave == 1) {
        float a = 0.f;
        const float* w = F + O_WGH2T + 4096 + lane;
        for (int k = 0; k < DH; k++) a += w[k*DH] * s_hprep[k];
        cst(&F[O_U21 + idx], a);
      } else if (wave == 2) {
        float hp = s_hprep[lane];
        float a1 = hp * F[O_WARH1 + DH + lane];
        float a2 = hp * F[O_WARH2 + DH + lane];
        for (int o = 32; o >= 1; o >>= 1) { a1 += __shfl_xor(a1, o, 64); a2 += __shfl_xor(a2, o, 64); }
        if (lane == 0) { F[O_S1 + i] = a1; cst(&F[O_S21 + i], a2); }
      }
    } else {
      // ---- OUT for step t
      if (wave == 0 && lane < 2) {
        float a = 0.f;
        if (m_i) {
          a = F[O_BOUT + lane];
          const float* wo = F + O_WOUT + lane*DH;
          for (int h = 0; h < DH; h++) a += s_hprep[h] * wo[h];
        }
        stf(out, (t*NN + i)*2 + lane, a, isf32);
      }
      // ---- fused LSTM(t+1) + prep p=0 (row-local)
      if (t < NSTEP - 1) { __syncthreads(); lstm_prep(t + 1); }
    }
    if (ph != 2*NSTEP - 1) gbar(bar, ++gen, grp);  // last phase: no barrier needed
  }

  // ---- finalize: own h/c rows + (block 0) scalars
  if (wave == 0) {
    stf(out, T_STEPS*NN*2 + i*DH + lane,          F[O_H + i*DH + lane], isf32);
    stf(out, T_STEPS*NN*2 + NN*DH + i*DH + lane,  F[O_C + i*DH + lane], isf32);
  }
  if (i == 0 && tid == 0) {
    float v1 = 0.f, v2 = 0.f, v3 = 0.f;
    for (int t = 0; t < NSTEP; t++) {
      float sg = cld(&F[O_ACC + t*4 + 0]), sn = cld(&F[O_ACC + t*4 + 1]);
      float sp = cld(&F[O_ACC + t*4 + 2]), sm = cld(&F[O_ACC + t*4 + 3]);
      v1 += sg / (sn * 64.f + 1e-6f);
      v2 += sp / (sm + 1e-6f);
      v3 += sn / 192.f;
    }
    int base = T_STEPS*NN*2 + 2*NN*DH;
    stf(out, base + 0, v1 / 20.f, isf32);
    stf(out, base + 1, v2 / 20.f, isf32);
    stf(out, base + 2, v3 / 20.f, isf32);
  }
}

extern "C" void kernel_launch(void* const* d_in, const int* in_sizes, int n_in,
                              void* d_out, int out_size, void* d_ws, size_t ws_size,
                              hipStream_t stream) {
  float* F = (float*)d_ws;
  unsigned* bar = (unsigned*)(F + O_GBAR);
  hipMemsetAsync((void*)bar, 0, 4096, stream);
  k_all<<<NB, NTH, 0, stream>>>(
      F, bar,
      d_in[0], d_in[1], (const int*)d_in[18], (const int*)d_in[19], d_out,
      d_in[3], d_in[4], d_in[5], d_in[6], d_in[7], d_in[8], d_in[9], d_in[10],
      d_in[11], d_in[12], d_in[13], d_in[14], d_in[15], d_in[16], d_in[17]);
}

// Round 10
// 648.301 us; speedup vs baseline: 2.2602x; 2.2403x over previous
//
#include <hip/hip_runtime.h>
#include <hip/hip_bf16.h>

#define T_STEPS 20
#define NSTEP   19
#define NN      192
#define DH      64
#define DE      32

// ---------------- workspace float offsets ----------------
// UH0/UH1: interleaved float2 {u2, hw} per (row, h) — one 8B load in P3.
enum : int {
  O_H     = 0,                 // committed h   [N][64]
  O_C     = O_H    + NN*DH,
  O_UH0   = O_C    + NN*DH,    // [N][64] float2 {U20, HW0}  (LSTM out, gcn0 in)
  O_UH1   = O_UH0  + 2*NN*DH,  // [N][64] float2 {U21, HW1}  (gcn0 out, gcn1 in)
  O_CW    = O_UH1  + 2*NN*DH,  // working c
  O_OG    = O_CW   + NN*DH,    // LSTM o-gate
  O_U1    = O_OG   + NN*DH,    // h_i-part of gate preact (row-local)
  O_S1    = O_U1   + NN*DH,
  O_S20   = O_S1   + NN,
  O_S21   = O_S20  + NN,
  O_ACC   = O_S21  + NN,       // [19][4]: sg, sn, sp, sm
  O_WIHT  = O_ACC  + NSTEP*4 + 4,  // [e][G] 8192  (zeroed state region ends here)
  O_WHHT  = O_WIHT + 8192,         // [k][G] 16384
  O_BIH   = O_WHHT + 16384,        // 256 (b_ih+b_hh)
  O_WIN   = O_BIH  + 256,
  O_BIN   = O_WIN  + 64,
  O_WRELF = O_BIN  + 32,           // 128  [p][d][c]
  O_BRELF = O_WRELF+ 128,
  O_WGR   = O_BRELF+ 64,           // 4096 [p][h][d<32]
  O_WGH1T = O_WGR  + 4096,         // 8192 [p][k][h]
  O_WGH2T = O_WGH1T+ 8192,
  O_BGATE = O_WGH2T+ 8192,
  O_WARR  = O_BGATE+ 128,
  O_WARH1 = O_WARR + 64,
  O_WARH2 = O_WARH1+ 128,
  O_BAR   = O_WARH2+ 128,
  O_WNEIT = O_BAR  + 4,            // 8192 [p][k][h]
  O_WOUT  = O_WNEIT+ 8192,
  O_BOUT  = O_WOUT + 128,
  O_ISF   = O_BOUT + 2,            // dtype flag (written by k_init)
  O_TOTAL = O_ISF  + 1
};

typedef unsigned long long ull;

__device__ __forceinline__ float bf2f(__hip_bfloat16 v) { return __bfloat162float(v); }
__device__ __forceinline__ float sigm(float x) { return 1.0f / (1.0f + __expf(-x)); }
__device__ __forceinline__ float tanh_fast(float x) {
  float e = __expf(-2.0f * fabsf(x));
  float r = (1.0f - e) / (1.0f + e);
  return copysignf(r, x);
}

// dtype-flex input load / output store
__device__ __forceinline__ float ldf(const void* p, int idx, int isf32) {
  if (isf32) return ((const float*)p)[idx];
  return bf2f(((const __hip_bfloat16*)p)[idx]);
}
__device__ __forceinline__ void stf(void* p, int idx, float v, int isf32) {
  if (isf32) ((float*)p)[idx] = v;
  else       ((__hip_bfloat16*)p)[idx] = __float2bfloat16(v);
}

// read cached dtype flag (one scalar load; replaces per-launch 1024-hw scan)
__device__ __forceinline__ int read_isf(const float* F, int tid, int* s_isf) {
  if (tid == 0) *s_isf = (int)F[O_ISF];
  __syncthreads();
  return *s_isf;
}

// LSTM step t for row i + prep for gcn p=0. If load_hc, wave0 loads committed
// H/C from F; else caller pre-filled s_hc/s_cc (before any sync).
__device__ __forceinline__ void lstm_prep_dev(
    float* __restrict__ F, const void* __restrict__ nnorm, int isf32,
    int t, int i, int tid, int wave, int lane, int load_hc,
    float* s_x, float* s_hc, float* s_cc, float* s_gates, float* s_h1)
{
  if (load_hc && wave == 0) { s_hc[lane] = F[O_H + i*DH + lane]; s_cc[lane] = F[O_C + i*DH + lane]; }
  if (wave == 1 && lane < DE) {
    float nx = ldf(nnorm, (t*NN + i)*2 + 0, isf32);
    float ny = ldf(nnorm, (t*NN + i)*2 + 1, isf32);
    s_x[lane] = fmaxf(nx*F[O_WIN + lane*2] + ny*F[O_WIN + lane*2 + 1] + F[O_BIN + lane], 0.f);
  }
  __syncthreads();
  {
    int G = tid;                                   // gate-major: i,f,g,o
    float acc = F[O_BIH + G];
    for (int e = 0; e < DE; e++) acc += F[O_WIHT + e*256 + G] * s_x[e];
    for (int k = 0; k < DH; k++) acc += F[O_WHHT + k*256 + G] * s_hc[k];
    s_gates[G] = acc;
  }
  __syncthreads();
  if (wave == 0) {
    float ig = sigm(s_gates[lane]);
    float fg = sigm(s_gates[64 + lane]);
    float gg = tanh_fast(s_gates[128 + lane]);
    float og = sigm(s_gates[192 + lane]);
    float c1 = fg * s_cc[lane] + ig * gg;
    float h1 = og * tanh_fast(c1);
    int idx = i*DH + lane;
    F[O_CW  + idx] = c1;
    F[O_UH0 + 2*idx + 1] = h1;                     // HW0 (.y)
    F[O_OG  + idx] = og;
    s_h1[lane] = h1;
  }
  __syncthreads();
  {
    int idx = i*DH + lane;
    if (wave == 0) {
      float a = 0.f;
      const float* w = F + O_WGH1T + lane;         // p=0
      for (int k = 0; k < DH; k++) a += w[k*DH] * s_h1[k];
      F[O_U1 + idx] = a;
    } else if (wave == 1) {
      float a = 0.f;
      const float* w = F + O_WGH2T + lane;         // p=0
      for (int k = 0; k < DH; k++) a += w[k*DH] * s_h1[k];
      F[O_UH0 + 2*idx] = a;                        // U20 (.x)
    } else if (wave == 2) {
      float hp = s_h1[lane];
      float a1 = hp * F[O_WARH1 + lane];
      float a2 = hp * F[O_WARH2 + lane];
      for (int o = 32; o >= 1; o >>= 1) { a1 += __shfl_xor(a1, o, 64); a2 += __shfl_xor(a2, o, 64); }
      if (lane == 0) { F[O_S1 + i] = a1; F[O_S20 + i] = a2; }
    }
  }
}

// ---------------- init: detect dtype, zero state, convert/transpose weights ----
__global__ __launch_bounds__(256) void k_init(float* __restrict__ F,
                       void* __restrict__ out,
                       const void* w_in,  const void* b_in,
                       const void* w_ih,  const void* w_hh,
                       const void* b_ih,  const void* b_hh,
                       const void* w_rel, const void* b_rel,
                       const void* w_gate,const void* b_gate,
                       const void* w_ar,  const void* b_ar,
                       const void* w_nei, const void* w_out,
                       const void* b_out) {
  __shared__ int s_isf;
  const int wave = threadIdx.x >> 6, lane = threadIdx.x & 63;
  // dtype detect: fp32 reinterpreted as bf16 half-words is ~49% |v|>4-or-NaN;
  // real bf16 (sigma 0.1) never is. (proven r3-r9)
  if (wave == 0) {
    const unsigned short* u = (const unsigned short*)w_gate;
    int bad = 0;
    for (int x = lane; x < 1024; x += 64) {
      float v = __uint_as_float(((unsigned)u[x]) << 16);
      if (!(fabsf(v) <= 4.0f)) bad++;
    }
    for (int o = 32; o >= 1; o >>= 1) bad += __shfl_xor(bad, o, 64);
    if (lane == 0) s_isf = (bad > 64);
  }
  __syncthreads();
  const int isf32 = s_isf;
  if (blockIdx.x == 0 && threadIdx.x == 0) F[O_ISF] = (float)isf32;

  int tid = blockIdx.x * blockDim.x + threadIdx.x;
  int stride = gridDim.x * blockDim.x;
  for (int x = tid; x < O_WIHT; x += stride) F[x] = 0.f;
  for (int x = tid; x < NN*2;  x += stride) stf(out, (T_STEPS-1)*NN*2 + x, 0.f, isf32);
  for (int x = tid; x < 8192;  x += stride) { int e = x >> 8, G = x & 255; F[O_WIHT + x] = ldf(w_ih, G*32 + e, isf32); }
  for (int x = tid; x < 16384; x += stride) { int k = x >> 8, G = x & 255; F[O_WHHT + x] = ldf(w_hh, G*64 + k, isf32); }
  for (int x = tid; x < 256;   x += stride) F[O_BIH + x] = ldf(b_ih, x, isf32) + ldf(b_hh, x, isf32);
  for (int x = tid; x < 64;    x += stride) F[O_WIN + x] = ldf(w_in, x, isf32);
  for (int x = tid; x < 32;    x += stride) F[O_BIN + x] = ldf(b_in, x, isf32);
  for (int x = tid; x < 128;   x += stride) F[O_WRELF + x] = ldf(w_rel, x, isf32);
  for (int x = tid; x < 64;    x += stride) F[O_BRELF + x] = ldf(b_rel, x, isf32);
  for (int x = tid; x < 4096;  x += stride) { int p = x >> 11, h = (x >> 5) & 63, d = x & 31;
    F[O_WGR + x] = ldf(w_gate, p*10240 + h*160 + d, isf32); }
  for (int x = tid; x < 8192;  x += stride) { int p = x >> 12, k = (x >> 6) & 63, h = x & 63;
    F[O_WGH1T + x] = ldf(w_gate, p*10240 + h*160 + 32 + k, isf32); }
  for (int x = tid; x < 8192;  x += stride) { int p = x >> 12, k = (x >> 6) & 63, h = x & 63;
    F[O_WGH2T + x] = ldf(w_gate, p*10240 + h*160 + 96 + k, isf32); }
  for (int x = tid; x < 128;   x += stride) F[O_BGATE + x] = ldf(b_gate, x, isf32);
  for (int x = tid; x < 64;    x += stride) { int p = x >> 5, d = x & 31; F[O_WARR + x] = ldf(w_ar, p*160 + d, isf32); }
  for (int x = tid; x < 128;   x += stride) { int p = x >> 6, k = x & 63; F[O_WARH1 + x] = ldf(w_ar, p*160 + 32 + k, isf32); }
  for (int x = tid; x < 128;   x += stride) { int p = x >> 6, k = x & 63; F[O_WARH2 + x] = ldf(w_ar, p*160 + 96 + k, isf32); }
  for (int x = tid; x < 2;     x += stride) F[O_BAR + x] = ldf(b_ar, x, isf32);
  for (int x = tid; x < 8192;  x += stride) { int p = x >> 12, k = (x >> 6) & 63, h = x & 63;
    F[O_WNEIT + x] = ldf(w_nei, p*4096 + h*64 + k, isf32); }
  for (int x = tid; x < 128;   x += stride) F[O_WOUT + x] = ldf(w_out, x, isf32);
  for (int x = tid; x < 2;     x += stride) F[O_BOUT + x] = ldf(b_out, x, isf32);
}

// ---------------- LSTM t=0 + prep for gcn0 ----------------
__global__ __launch_bounds__(256) void k_lstm0(float* __restrict__ F,
                                               const void* __restrict__ nnorm) {
  __shared__ float s_x[DE], s_hc[DH], s_cc[DH], s_gates[4*DH], s_h1[DH];
  __shared__ int s_isf;
  const int tid = threadIdx.x, wave = tid >> 6, lane = tid & 63;
  const int isf32 = read_isf(F, tid, &s_isf);
  lstm_prep_dev(F, nnorm, isf32, 0, blockIdx.x, tid, wave, lane, 1,
                s_x, s_hc, s_cc, s_gates, s_h1);
}

// ---------------- GCN pass p for step t (p==1 fuses commit/out/LSTM(t+1)/fin) --
__global__ __launch_bounds__(256) void k_gcn(float* __restrict__ F,
                                             const void* __restrict__ nabs,
                                             const void* __restrict__ nnorm,
                                             const int* __restrict__ seq,
                                             const int* __restrict__ nei,
                                             void* __restrict__ out,
                                             int t, int p, int last) {
  // s_rt[j][33]: pad-33 -> P1 writes hit banks (j+d)%32 (2-way alias = free),
  // P3 reads are contiguous per j (compiler can merge to ds_read2/b64).
  __shared__ float s_rt[NN*33];                    // 24.75 KB
  __shared__ float s_score[NN], s_pos[NN], s_neif[NN];
  __shared__ int   s_jlist[NN];
  __shared__ float s_red[4*DH], s_v1[4], s_msg[DH], s_hprep[DH];
  __shared__ float s_x[DE], s_hc[DH], s_cc[DH], s_gates[4*DH], s_h1[DH];
  __shared__ int   s_isf, s_nv;

  const int tid = threadIdx.x, wave = tid >> 6, lane = tid & 63;
  const int i = blockIdx.x;
  const int isf32 = read_isf(F, tid, &s_isf);
  const int m_i = seq[t*NN + i] > 0;
  const int UHr = p ? O_UH1 : O_UH0;
  const int S2r = p ? O_S21 : O_S20;

  // ---- P1: mask, r values, raw scores
  if (wave < 3) {
    int j  = wave*64 + lane;
    int nf = m_i && (seq[t*NN + j] > 0) && (nei[(t*NN + i)*NN + j] > 0);
    s_neif[j] = nf ? 1.f : 0.f;
    float sc = 0.f;
    if (nf) {
      float cx = ldf(nabs, (t*NN + i)*2 + 0, isf32) - ldf(nabs, (t*NN + j)*2 + 0, isf32);
      float cy = ldf(nabs, (t*NN + i)*2 + 1, isf32) - ldf(nabs, (t*NN + j)*2 + 1, isf32);
      const float* wr = F + O_WRELF + p*64;
      const float* br = F + O_BRELF + p*32;
      const float* wa = F + O_WARR  + p*32;
      float dot = 0.f;
      for (int d = 0; d < 32; d++) {
        float rv = fmaxf(cx*wr[2*d] + cy*wr[2*d+1] + br[d], 0.f);
        s_rt[j*33 + d] = rv;
        dot += rv * wa[d];
      }
      sc = dot + F[O_S1 + i] + F[S2r + j] + F[O_BAR + p];
    }
    s_score[j] = sc;
  }
  __syncthreads();

  // ---- P2: masked softmax + j-list compaction + (p==0) row stats (wave 0)
  if (wave == 0) {
    float n0 = s_neif[lane], n1 = s_neif[64+lane], n2 = s_neif[128+lane];
    float sc0 = s_score[lane], sc1 = s_score[64+lane], sc2 = s_score[128+lane];
    const float NEG = -3.0e38f;
    float mx = fmaxf(fmaxf(n0 > 0.f ? sc0 : NEG, n1 > 0.f ? sc1 : NEG),
                     n2 > 0.f ? sc2 : NEG);
    for (int o = 32; o >= 1; o >>= 1) mx = fmaxf(mx, __shfl_xor(mx, o, 64));
    float e0 = (n0 > 0.f) ? __expf(sc0 - mx) : 0.f;
    float e1 = (n1 > 0.f) ? __expf(sc1 - mx) : 0.f;
    float e2 = (n2 > 0.f) ? __expf(sc2 - mx) : 0.f;
    float s = e0 + e1 + e2;
    for (int o = 32; o >= 1; o >>= 1) s += __shfl_xor(s, o, 64);
    float inv = (s > 0.f) ? 1.0f / s : 0.f;
    float p0 = e0*inv, p1 = e1*inv, p2 = e2*inv;
    s_pos[lane] = p0; s_pos[64+lane] = p1; s_pos[128+lane] = p2;
    ull m0 = __ballot(n0 > 0.f), m1 = __ballot(n1 > 0.f), m2 = __ballot(n2 > 0.f);
    ull lt = (1ull << lane) - 1ull;
    int c0 = __popcll(m0), c1 = __popcll(m1);
    if (n0 > 0.f) s_jlist[__popcll(m0 & lt)] = lane;
    if (n1 > 0.f) s_jlist[c0 + __popcll(m1 & lt)] = 64 + lane;
    if (n2 > 0.f) s_jlist[c0 + c1 + __popcll(m2 & lt)] = 128 + lane;
    if (lane == 0) s_nv = c0 + c1 + __popcll(m2);
    if (p == 0 && m_i) {
      float cnt = n0 + n1 + n2;
      float pm  = fmaxf(fmaxf(p0, p1), p2);
      for (int o = 32; o >= 1; o >>= 1) {
        cnt += __shfl_xor(cnt, o, 64);
        pm   = fmaxf(pm, __shfl_xor(pm, o, 64));
      }
      if (lane == 0 && cnt > 0.f) {
        atomicAdd(&F[O_ACC + t*4 + 1], cnt);
        atomicAdd(&F[O_ACC + t*4 + 2], pm);
        atomicAdd(&F[O_ACC + t*4 + 3], 1.f);
      }
    }
  }
  __syncthreads();

  // ---- P3: gates + msg partials over compacted list (lane = h).
  // One float2 load per j (u2,hw interleaved), prefetched 1 iter ahead.
  {
    float msg = 0.f, v1 = 0.f;
    const int nv = s_nv;
    if (m_i && nv > 0) {
      float wreg[32];
      const float* wgp = F + O_WGR + p*2048 + lane*32;
#pragma unroll
      for (int d = 0; d < 32; d++) wreg[d] = wgp[d];
      float basev = F[O_U1 + i*DH + lane] + F[O_BGATE + p*DH + lane];
      const float2* UH2 = (const float2*)(F + UHr);
      int k = wave;
      int jn = (k < nv) ? s_jlist[k] : 0;
      float2 uhn = (k < nv) ? UH2[jn*DH + lane] : make_float2(0.f, 0.f);
      for (; k < nv; k += 4) {
        int j = jn;
        float2 uh = uhn;
        int kn = k + 4;
        if (kn < nv) { jn = s_jlist[kn]; uhn = UH2[jn*DH + lane]; }
        float acc = basev + uh.x;
        const float* rr = &s_rt[j*33];
#pragma unroll
        for (int d = 0; d < 32; d++) acc += rr[d] * wreg[d];
        float g = sigm(acc);
        v1 += g;
        msg += s_pos[j] * g * uh.y;
      }
    }
    s_red[wave*DH + lane] = msg;
    for (int o = 32; o >= 1; o >>= 1) v1 += __shfl_xor(v1, o, 64);
    if (lane == 0) s_v1[wave] = v1;
  }
  __syncthreads();

  // ---- T1: combine partials + v1 atomic (wave 0)
  if (wave == 0) {
    s_msg[lane] = s_red[lane] + s_red[64+lane] + s_red[128+lane] + s_red[192+lane];
    if (p == 0 && m_i && lane == 0) {
      float v1t = s_v1[0] + s_v1[1] + s_v1[2] + s_v1[3];
      atomicAdd(&F[O_ACC + t*4 + 0], v1t);
    }
  }
  __syncthreads();

  // ---- T2: c/h update; publish (p=0) or commit (p=1)
  if (wave == 0) {
    int idx = i*DH + lane;
    float hcom, ccom = 0.f;
    if (m_i) {
      float cn = F[O_CW + idx];
      const float* wn = F + O_WNEIT + p*4096 + lane;
      for (int k = 0; k < DH; k++) cn += s_msg[k] * wn[k*DH];
      hcom = F[O_OG + idx] * tanh_fast(cn);
      F[O_CW + idx] = cn;
      ccom = cn;
      if (p == 1) { F[O_H + idx] = hcom; F[O_C + idx] = ccom; }
    } else {
      hcom = F[UHr + 2*idx + 1];             // gcn is identity for masked rows
    }
    if (p == 0) F[O_UH1 + 2*idx + 1] = hcom; // publish HW1 (.y), all rows
    s_hprep[lane] = hcom;
    if (p == 1) {                            // committed state for LSTM / final
      s_hc[lane] = m_i ? hcom : F[O_H + idx];
      s_cc[lane] = m_i ? ccom : F[O_C + idx];
    }
  }
  __syncthreads();

  if (p == 0) {
    // ---- PREP for p=1 from post-gcn0 h
    int idx = i*DH + lane;
    if (wave == 0) {
      float a = 0.f;
      const float* w = F + O_WGH1T + 4096 + lane;   // p=1
      for (int k = 0; k < DH; k++) a += w[k*DH] * s_hprep[k];
      F[O_U1 + idx] = a;
    } else if (wave == 1) {
      float a = 0.f;
      const float* w = F + O_WGH2T + 4096 + lane;   // p=1
      for (int k = 0; k < DH; k++) a += w[k*DH] * s_hprep[k];
      F[O_UH1 + 2*idx] = a;                         // U21 (.x), all rows
    } else if (wave == 2) {
      float hp = s_hprep[lane];
      float a1 = hp * F[O_WARH1 + DH + lane];       // p=1
      float a2 = hp * F[O_WARH2 + DH + lane];
      for (int o = 32; o >= 1; o >>= 1) { a1 += __shfl_xor(a1, o, 64); a2 += __shfl_xor(a2, o, 64); }
      if (lane == 0) { F[O_S1 + i] = a1; F[O_S21 + i] = a2; }
    }
  } else {
    // ---- OUT row for step t
    if (wave == 0 && lane < 2) {
      float a = 0.f;
      if (m_i) {
        a = F[O_BOUT + lane];
        const float* wo = F + O_WOUT + lane*DH;
        for (int h = 0; h < DH; h++) a += s_hprep[h] * wo[h];
      }
      stf(out, (t*NN + i)*2 + lane, a, isf32);
    }
    if (!last) {
      // ---- fused LSTM(t+1) + prep p=0 (s_hc/s_cc set in T2, synced above)
      lstm_prep_dev(F, nnorm, isf32, t + 1, i, tid, wave, lane, 0,
                    s_x, s_hc, s_cc, s_gates, s_h1);
    } else {
      // ---- finalize: own-row h/c + (block 0) scalars
      if (wave == 0) stf(out, T_STEPS*NN*2 + i*DH + lane,         s_hc[lane], isf32);
      if (wave == 1) stf(out, T_STEPS*NN*2 + NN*DH + i*DH + lane, s_cc[lane], isf32);
      if (i == 0 && tid == 0) {
        float v1 = 0.f, v2 = 0.f, v3 = 0.f;
        for (int tt = 0; tt < NSTEP; tt++) {
          float sg = F[O_ACC + tt*4 + 0], sn = F[O_ACC + tt*4 + 1];
          float sp = F[O_ACC + tt*4 + 2], sm = F[O_ACC + tt*4 + 3];
          v1 += sg / (sn * 64.f + 1e-6f);
          v2 += sp / (sm + 1e-6f);
          v3 += sn / 192.f;
        }
        int base = T_STEPS*NN*2 + 2*NN*DH;
        stf(out, base + 0, v1 / 20.f, isf32);
        stf(out, base + 1, v2 / 20.f, isf32);
        stf(out, base + 2, v3 / 20.f, isf32);
      }
    }
  }
}

extern "C" void kernel_launch(void* const* d_in, const int* in_sizes, int n_in,
                              void* d_out, int out_size, void* d_ws, size_t ws_size,
                              hipStream_t stream) {
  const void* nabs  = d_in[0];
  const void* nnorm = d_in[1];
  const int* seq = (const int*)d_in[18];
  const int* nei = (const int*)d_in[19];
  float* F = (float*)d_ws;

  k_init<<<NN, 256, 0, stream>>>(F, d_out,
      d_in[3], d_in[4], d_in[5], d_in[6], d_in[7], d_in[8], d_in[9], d_in[10],
      d_in[11], d_in[12], d_in[13], d_in[14], d_in[15], d_in[16], d_in[17]);
  k_lstm0<<<NN, 256, 0, stream>>>(F, nnorm);
  for (int t = 0; t < NSTEP; t++) {
    k_gcn<<<NN, 256, 0, stream>>>(F, nabs, nnorm, seq, nei, d_out, t, 0, 0);
    k_gcn<<<NN, 256, 0, stream>>>(F, nabs, nnorm, seq, nei, d_out, t, 1, t == NSTEP - 1);
  }
}